// Round 11
// baseline (142.739 us; speedup 1.0000x reference)
//
#include <hip/hip_runtime.h>

// DynamicLinBertSelfAttention on MI355X (gfx950).  R11: attn probs write
// coalesced via fp32 LDS staging (overlays dead kpl region); out_gemm ported
// to R7 triple-buffer schedule (counted vmcnt(3)). Rest frozen from R10.
//
// d_out layout (fp32): [0,8388608) output, [8388608,16777216) attn_probs, [16777216] curr_r.

typedef unsigned short u16;
typedef short s16x8 __attribute__((ext_vector_type(8)));
typedef unsigned short u16x8 __attribute__((ext_vector_type(8)));
typedef unsigned short u16x4 __attribute__((ext_vector_type(4)));
typedef float f32x4 __attribute__((ext_vector_type(4)));

#define GLL16(gp, lp) __builtin_amdgcn_global_load_lds( \
    (const __attribute__((address_space(1))) void*)(gp), \
    (__attribute__((address_space(3))) void*)(lp), 16, 0, 0)

__device__ __forceinline__ u16 f2bf(float f) {
    unsigned u = __float_as_uint(f);
    u += 0x7fffu + ((u >> 16) & 1u);   // RNE (inputs finite)
    return (u16)(u >> 16);
}

__device__ __forceinline__ f32x4 mfma16(s16x8 a, s16x8 b, f32x4 c) {
    return __builtin_amdgcn_mfma_f32_16x16x32_bf16(a, b, c, 0, 0, 0);
}

// ---------------- K1: fused prep — hs cast+var, weight cast, proj transpose, biases ----------------
__global__ __launch_bounds__(256) void prep_k(const float* __restrict__ hs,
        u16* __restrict__ hsb, double* __restrict__ red,
        const float* __restrict__ w0, const float* __restrict__ w1,
        const float* __restrict__ w2, const float* __restrict__ w3,
        u16* __restrict__ wout,
        const float* __restrict__ p0, const float* __restrict__ p1,
        u16* __restrict__ q0, u16* __restrict__ q1,
        const float* __restrict__ bq, const float* __restrict__ bk,
        const float* __restrict__ bv, float* __restrict__ biascat) {
    __shared__ float tl[64][65];
    __shared__ double sa[256], sb[256];
    int bid = blockIdx.x, t = threadIdx.x;
    if (bid < 1024) {                 // hs cast + fp64 variance partials
        size_t base = (size_t)bid * 8192;
        double s = 0.0, s2 = 0.0;
        #pragma unroll
        for (int i = 0; i < 4; ++i) {
            size_t idx = base + (size_t)i * 2048 + (size_t)t * 8;
            float4 a = *(const float4*)(hs + idx);
            float4 c = *(const float4*)(hs + idx + 4);
            s  += (double)a.x + (double)a.y + (double)a.z + (double)a.w
                + (double)c.x + (double)c.y + (double)c.z + (double)c.w;
            s2 += (double)a.x * a.x + (double)a.y * a.y + (double)a.z * a.z + (double)a.w * a.w
                + (double)c.x * c.x + (double)c.y * c.y + (double)c.z * c.z + (double)c.w * c.w;
            u16x8 o;
            o[0] = f2bf(a.x); o[1] = f2bf(a.y); o[2] = f2bf(a.z); o[3] = f2bf(a.w);
            o[4] = f2bf(c.x); o[5] = f2bf(c.y); o[6] = f2bf(c.z); o[7] = f2bf(c.w);
            *(u16x8*)(hsb + idx) = o;
        }
        sa[t] = s; sb[t] = s2;
        __syncthreads();
        for (int o = 128; o > 0; o >>= 1) {
            if (t < o) { sa[t] += sa[t + o]; sb[t] += sb[t + o]; }
            __syncthreads();
        }
        if (t == 0) { red[bid * 2] = sa[0]; red[bid * 2 + 1] = sb[0]; }
    } else if (bid < 3072) {          // weight cast
        int bid2 = bid - 1024;
        int mat = bid2 >> 9;
        int off = ((bid2 & 511) * 256 + t) * 8;
        const float* src = (mat == 0) ? w0 : (mat == 1) ? w1 : (mat == 2) ? w2 : w3;
        float4 a = *(const float4*)(src + off);
        float4 c = *(const float4*)(src + off + 4);
        u16x8 o;
        o[0] = f2bf(a.x); o[1] = f2bf(a.y); o[2] = f2bf(a.z); o[3] = f2bf(a.w);
        o[4] = f2bf(c.x); o[5] = f2bf(c.y); o[6] = f2bf(c.z); o[7] = f2bf(c.w);
        *(u16x8*)(wout + (size_t)mat * 1048576 + off) = o;
    } else if (bid < 4096) {          // proj transpose-cast
        int bid2 = bid - 3072;
        int which = bid2 >> 9, bi = bid2 & 511;
        const float* p = which ? p1 : p0;
        u16* pt = which ? q1 : q0;
        int h = bi >> 5, lb = bi & 31;
        {
            int l = t >> 2, r0 = (t & 3) * 16;
            const float* src = p + ((size_t)(h * 2048 + lb * 64 + l)) * 64 + r0;
            #pragma unroll
            for (int u = 0; u < 4; ++u) {
                float4 v = *(const float4*)(src + u * 4);
                tl[l][r0 + u * 4 + 0] = v.x; tl[l][r0 + u * 4 + 1] = v.y;
                tl[l][r0 + u * 4 + 2] = v.z; tl[l][r0 + u * 4 + 3] = v.w;
            }
        }
        __syncthreads();
        {
            int r = t >> 2, l0 = (t & 3) * 16;
            u16x8 o0, o1;
            #pragma unroll
            for (int j = 0; j < 8; ++j) { o0[j] = f2bf(tl[l0 + j][r]); o1[j] = f2bf(tl[l0 + 8 + j][r]); }
            u16* dst = pt + ((size_t)(h * 64 + r)) * 2048 + lb * 64 + l0;
            *(u16x8*)dst = o0;
            *(u16x8*)(dst + 8) = o1;
        }
    } else {                          // bias concat [3072]
        for (int i = t; i < 3072; i += 256) {
            float v = (i < 1024) ? bq[i] : (i < 2048) ? bk[i - 1024] : bv[i - 2048];
            biascat[i] = v;
        }
    }
}

// ---------------- QKV GEMM (R7 triple-buffer, measured 56us) ----------------
__global__ __launch_bounds__(512, 2) void qkv_gemm_k(const u16* __restrict__ Ag,
        const u16* __restrict__ Wcat, const float* __restrict__ biascat,
        u16* __restrict__ C) {
    __shared__ u16 lds[61440];
    int bid = blockIdx.x;
    int swz = (bid & 7) * 32 + (bid >> 3);    // XCD-aware (256 % 8 == 0)
    int bm = swz >> 3, bn = swz & 7;
    int t = threadIdx.x, lane = t & 63, w = t >> 6, wr = w >> 2, wc = w & 3;

    int srow = w * 16 + (lane >> 2);
    int slog = (((lane & 3) ^ ((lane >> 3) & 3)) << 3);
    const u16* asrc0 = Ag + (size_t)(bm * 256 + srow) * 1024 + slog;
    const u16* bsrc0 = Wcat + (size_t)(bn * 384 + srow) * 1024 + slog;

#define STAGEA(kts, h) GLL16(asrc0 + (h) * 131072 + (kts) * 32, \
                             &lds[((kts) % 3) * 20480 + (h) * 4096 + w * 512])
#define STAGEB(kts, h) GLL16(bsrc0 + (h) * 131072 + (kts) * 32, \
                             &lds[((kts) % 3) * 20480 + 8192 + (h) * 4096 + w * 512])

    int pcol = (((lane >> 4) ^ (((lane & 15) >> 1) & 3)) << 3);
    int arow0 = (wr * 128 + (lane & 15)) * 32 + pcol;
    int brow0 = 8192 + (wc * 96 + (lane & 15)) * 32 + pcol;

    f32x4 zero4 = {0.f, 0.f, 0.f, 0.f};
    f32x4 acc[8][6];
    #pragma unroll
    for (int m = 0; m < 8; ++m)
        #pragma unroll
        for (int n = 0; n < 6; ++n) acc[m][n] = zero4;

    STAGEA(0, 0); STAGEA(0, 1); STAGEB(0, 0); STAGEB(0, 1); STAGEB(0, 2);
    STAGEA(1, 0); STAGEA(1, 1); STAGEB(1, 0); STAGEB(1, 1); STAGEB(1, 2);
    asm volatile("s_waitcnt vmcnt(5)" ::: "memory");
    __builtin_amdgcn_s_barrier();
    asm volatile("" ::: "memory");

    for (int kt = 0; kt < 32; ++kt) {
        int b3 = (kt % 3) * 20480;
        int abase = b3 + arow0;
        int bbase = b3 + brow0;
        s16x8 af[8], bf0, bf1, bf2;

        // ---- phase 0: all A frags + B n0,n1,n2 ; stage kt+2 A0,A1,B0 ----
        #pragma unroll
        for (int m = 0; m < 8; ++m) af[m] = *(const s16x8*)&lds[abase + m * 512];
        bf0 = *(const s16x8*)&lds[bbase];
        bf1 = *(const s16x8*)&lds[bbase + 512];
        bf2 = *(const s16x8*)&lds[bbase + 1024];
        if (kt < 30) { STAGEA(kt + 2, 0); STAGEA(kt + 2, 1); STAGEB(kt + 2, 0); }
        __builtin_amdgcn_s_barrier();
        asm volatile("s_waitcnt lgkmcnt(0)" ::: "memory");
        __builtin_amdgcn_s_setprio(1);
        #pragma unroll
        for (int m = 0; m < 8; ++m) {
            acc[m][0] = mfma16(af[m], bf0, acc[m][0]);
            acc[m][1] = mfma16(af[m], bf1, acc[m][1]);
            acc[m][2] = mfma16(af[m], bf2, acc[m][2]);
        }
        __builtin_amdgcn_s_setprio(0);
        __builtin_amdgcn_s_barrier();
        asm volatile("" ::: "memory");

        // ---- phase 1: B n3,n4,n5 ; stage kt+2 B1,B2 ; counted vmcnt after MFMA ----
        bf0 = *(const s16x8*)&lds[bbase + 1536];
        bf1 = *(const s16x8*)&lds[bbase + 2048];
        bf2 = *(const s16x8*)&lds[bbase + 2560];
        if (kt < 30) { STAGEB(kt + 2, 1); STAGEB(kt + 2, 2); }
        __builtin_amdgcn_s_barrier();
        asm volatile("s_waitcnt lgkmcnt(0)" ::: "memory");
        __builtin_amdgcn_s_setprio(1);
        #pragma unroll
        for (int m = 0; m < 8; ++m) {
            acc[m][3] = mfma16(af[m], bf0, acc[m][3]);
            acc[m][4] = mfma16(af[m], bf1, acc[m][4]);
            acc[m][5] = mfma16(af[m], bf2, acc[m][5]);
        }
        __builtin_amdgcn_s_setprio(0);
        if (kt < 30) { asm volatile("s_waitcnt vmcnt(5)" ::: "memory"); }
        else if (kt == 30) { asm volatile("s_waitcnt vmcnt(0)" ::: "memory"); }
        __builtin_amdgcn_s_barrier();
        asm volatile("" ::: "memory");
    }

    float bias[6];
    #pragma unroll
    for (int n = 0; n < 6; ++n)
        bias[n] = biascat[bn * 384 + wc * 96 + n * 16 + (lane & 15)];
    #pragma unroll
    for (int m = 0; m < 8; ++m) {
        int row0 = bm * 256 + wr * 128 + m * 16 + ((lane >> 4) << 2);
        #pragma unroll
        for (int n = 0; n < 6; ++n) {
            int col = bn * 384 + wc * 96 + n * 16 + (lane & 15);
            #pragma unroll
            for (int v = 0; v < 4; ++v)
                C[(size_t)(row0 + v) * 3072 + col] = f2bf(acc[m][n][v] + bias[n]);
        }
    }
#undef STAGEA
#undef STAGEB
}

// ---------------- out-proj GEMM (triple-buffer): C[8192][1024] f32 = ctx @ Wo^T + bo ----------------
// 256x128 tile, BK=32, 8 waves (4M x 2N), per-wave 64x64. LDS 72KB = 3 x
// (A 8192 + B 4096 u16); stage kt+2 into idle buffer; counted vmcnt(3).
__global__ __launch_bounds__(512, 2) void out_gemm_k(const u16* __restrict__ Ag,
        const u16* __restrict__ Bg, const float* __restrict__ biasg,
        float* __restrict__ Cg) {
    __shared__ u16 lds[36864];
    int bid = blockIdx.x;
    int swz = (bid & 7) * 32 + (bid >> 3);
    int bm = swz >> 3, bn = swz & 7;
    int t = threadIdx.x, lane = t & 63, w = t >> 6, wr = w >> 1, wc = w & 1;

    int srow = w * 16 + (lane >> 2);
    int slog = (((lane & 3) ^ ((lane >> 3) & 3)) << 3);
    const u16* asrc0 = Ag + (size_t)(bm * 256 + srow) * 1024 + slog;
    const u16* bsrc0 = Bg + (size_t)(bn * 128 + srow) * 1024 + slog;

#define STAGEA(kts, h) GLL16(asrc0 + (h) * 131072 + (kts) * 32, \
                             &lds[((kts) % 3) * 12288 + (h) * 4096 + w * 512])
#define STAGEB(kts) GLL16(bsrc0 + (kts) * 32, \
                          &lds[((kts) % 3) * 12288 + 8192 + w * 512])

    int pcol = (((lane >> 4) ^ (((lane & 15) >> 1) & 3)) << 3);
    int arow0 = (wr * 64 + (lane & 15)) * 32 + pcol;
    int brow0 = 8192 + (wc * 64 + (lane & 15)) * 32 + pcol;

    f32x4 zero4 = {0.f, 0.f, 0.f, 0.f};
    f32x4 acc[4][4];
    #pragma unroll
    for (int m = 0; m < 4; ++m)
        #pragma unroll
        for (int n = 0; n < 4; ++n) acc[m][n] = zero4;

    STAGEA(0, 0); STAGEA(0, 1); STAGEB(0);
    STAGEA(1, 0); STAGEA(1, 1); STAGEB(1);
    asm volatile("s_waitcnt vmcnt(3)" ::: "memory");
    __builtin_amdgcn_s_barrier();
    asm volatile("" ::: "memory");

    for (int kt = 0; kt < 32; ++kt) {
        int b3 = (kt % 3) * 12288;
        int abase = b3 + arow0;
        int bbase = b3 + brow0;
        s16x8 af[4], bf0, bf1;

        // ---- phase 0: A frags + B n0,n1 ; stage kt+2 A0,A1 ----
        #pragma unroll
        for (int m = 0; m < 4; ++m) af[m] = *(const s16x8*)&lds[abase + m * 512];
        bf0 = *(const s16x8*)&lds[bbase];
        bf1 = *(const s16x8*)&lds[bbase + 512];
        if (kt < 30) { STAGEA(kt + 2, 0); STAGEA(kt + 2, 1); }
        __builtin_amdgcn_s_barrier();
        asm volatile("s_waitcnt lgkmcnt(0)" ::: "memory");
        __builtin_amdgcn_s_setprio(1);
        #pragma unroll
        for (int m = 0; m < 4; ++m) {
            acc[m][0] = mfma16(af[m], bf0, acc[m][0]);
            acc[m][1] = mfma16(af[m], bf1, acc[m][1]);
        }
        __builtin_amdgcn_s_setprio(0);
        __builtin_amdgcn_s_barrier();
        asm volatile("" ::: "memory");

        // ---- phase 1: B n2,n3 ; stage kt+2 B ; counted vmcnt after MFMA ----
        bf0 = *(const s16x8*)&lds[bbase + 1024];
        bf1 = *(const s16x8*)&lds[bbase + 1536];
        if (kt < 30) STAGEB(kt + 2);
        __builtin_amdgcn_s_barrier();
        asm volatile("s_waitcnt lgkmcnt(0)" ::: "memory");
        __builtin_amdgcn_s_setprio(1);
        #pragma unroll
        for (int m = 0; m < 4; ++m) {
            acc[m][2] = mfma16(af[m], bf0, acc[m][2]);
            acc[m][3] = mfma16(af[m], bf1, acc[m][3]);
        }
        __builtin_amdgcn_s_setprio(0);
        if (kt < 30) { asm volatile("s_waitcnt vmcnt(3)" ::: "memory"); }
        else if (kt == 30) { asm volatile("s_waitcnt vmcnt(0)" ::: "memory"); }
        __builtin_amdgcn_s_barrier();
        asm volatile("" ::: "memory");
    }

    float bias[4];
    #pragma unroll
    for (int n = 0; n < 4; ++n)
        bias[n] = biasg[bn * 128 + wc * 64 + n * 16 + (lane & 15)];
    #pragma unroll
    for (int m = 0; m < 4; ++m) {
        int row0 = bm * 256 + wr * 64 + m * 16 + ((lane >> 4) << 2);
        #pragma unroll
        for (int n = 0; n < 4; ++n) {
            int col = bn * 128 + wc * 64 + n * 16 + (lane & 15);
            #pragma unroll
            for (int v = 0; v < 4; ++v)
                Cg[(size_t)(row0 + v) * 1024 + col] = acc[m][n][v] + bias[n];
        }
    }
#undef STAGEA
#undef STAGEB
}

// ---------------- proj einsum v4: c=4 chunks of 512 l ----------------
__global__ __launch_bounds__(256) void proj_einsum_k(const u16* __restrict__ qkv,
        const u16* __restrict__ pt0, const u16* __restrict__ pt1,
        float* __restrict__ out0, float* __restrict__ out1) {
    __shared__ u16 kt[512 * 66];
    int c = blockIdx.x, h = blockIdx.y, z = blockIdx.z;
    int which = z >> 2, b = z & 3;
    const u16* kv = qkv + 1024 + which * 1024;
    const u16* pt = which ? pt1 : pt0;
    float* outp = which ? out1 : out0;
    int t = threadIdx.x, lane = t & 63, w = t >> 6;

    int tl = t >> 3, sd = (t & 7) * 8;
    const u16* kvp = kv + (size_t)(b * 2048 + c * 512 + tl) * 3072 + h * 64 + sd;
    #pragma unroll
    for (int half = 0; half < 2; ++half) {
        s16x8 g[8];
        #pragma unroll
        for (int i = 0; i < 8; ++i)
            g[i] = *(const s16x8*)(kvp + (size_t)(half * 8 + i) * 98304);
        #pragma unroll
        for (int i = 0; i < 8; ++i)
            *(s16x8*)&kt[(tl + 32 * (half * 8 + i)) * 66 + sd] = g[i];
    }
    __syncthreads();

    f32x4 zero4 = {0.f, 0.f, 0.f, 0.f};
    f32x4 acc[4] = {zero4, zero4, zero4, zero4};
    const u16* ptb_ = pt + (size_t)(h * 64 + (lane & 15)) * 2048 + c * 512 + ((lane >> 4) << 3);
    int gcol = w * 16 + (lane & 15);
    int gk0 = (lane >> 4) << 3;

    #pragma unroll
    for (int ks = 0; ks < 16; ++ks) {
        s16x8 bf;
        int kb = (ks * 32 + gk0) * 66 + gcol;
        #pragma unroll
        for (int j = 0; j < 8; ++j) bf[j] = (short)kt[kb + j * 66];
        #pragma unroll
        for (int m = 0; m < 4; ++m) {
            s16x8 af = *(const s16x8*)(ptb_ + (size_t)m * 32768 + ks * 32);
            acc[m] = mfma16(af, bf, acc[m]);
        }
    }

    float* ob = outp + (size_t)((c * 4 + b) * 16 + h) * 4096;
    #pragma unroll
    for (int m = 0; m < 4; ++m)
        #pragma unroll
        for (int v = 0; v < 4; ++v)
            ob[(m * 16 + ((lane >> 4) << 2) + v) * 64 + w * 16 + (lane & 15)] = acc[m][v];
}

// ---------------- reduce chunk partials -> bf16 KP [r][d] and VP [d][r]; +curr_r ----------------
__global__ __launch_bounds__(256) void reduce_kv_k(const float* __restrict__ kp_part,
        const float* __restrict__ vp_part, u16* __restrict__ kpb, u16* __restrict__ vpb,
        const double* __restrict__ red, int* __restrict__ currp, float* __restrict__ outr) {
    int h = blockIdx.x, b = blockIdx.y, zr = blockIdx.z, t = threadIdx.x;
    int r = zr * 16 + (t >> 4), d0 = (t & 15) * 4;
    int base = (b * 16 + h) * 4096 + r * 64 + d0;
    float4 sk = {0.f, 0.f, 0.f, 0.f}, sv = {0.f, 0.f, 0.f, 0.f};
    #pragma unroll
    for (int c = 0; c < 4; ++c) {
        float4 a = *(const float4*)&kp_part[c * 262144 + base];
        float4 g = *(const float4*)&vp_part[c * 262144 + base];
        sk.x += a.x; sk.y += a.y; sk.z += a.z; sk.w += a.w;
        sv.x += g.x; sv.y += g.y; sv.z += g.z; sv.w += g.w;
    }
    size_t ob = (size_t)(b * 16 + h) * 4096;
    u16x4 ok;
    ok[0] = f2bf(sk.x); ok[1] = f2bf(sk.y); ok[2] = f2bf(sk.z); ok[3] = f2bf(sk.w);
    *(u16x4*)&kpb[ob + r * 64 + d0] = ok;
    vpb[ob + (size_t)(d0 + 0) * 64 + r] = f2bf(sv.x);
    vpb[ob + (size_t)(d0 + 1) * 64 + r] = f2bf(sv.y);
    vpb[ob + (size_t)(d0 + 2) * 64 + r] = f2bf(sv.z);
    vpb[ob + (size_t)(d0 + 3) * 64 + r] = f2bf(sv.w);

    if (h == 0 && b == 0 && zr == 0) {   // curr_r (deterministic fp64)
        int lane = t & 63, bb = t >> 6;
        double s = 0.0, s2 = 0.0;
        #pragma unroll
        for (int j = 0; j < 4; ++j) {
            int idx = bb * 256 + j * 64 + lane;
            s += red[idx * 2]; s2 += red[idx * 2 + 1];
        }
        #pragma unroll
        for (int o = 1; o < 64; o <<= 1) { s += __shfl_xor(s, o); s2 += __shfl_xor(s2, o); }
        __shared__ double vs[4];
        if (lane == 0) {
            const double N = 2097152.0;
            vs[bb] = (s2 - s * s / N) / (N - 1.0);
        }
        __syncthreads();
        if (t == 0) {
            double mn = vs[0], mx = vs[0];
            for (int i = 1; i < 4; ++i) { mn = fmin(mn, vs[i]); mx = fmax(mx, vs[i]); }
            double mean = 0.0;
            for (int i = 0; i < 4; ++i) mean += (vs[i] - mn) / (mx - mn + 1e-6);
            mean *= 0.25;
            double rr = rint(16.0 + mean * 48.0);
            *currp = (int)rr;
            *outr = (float)rr;
        }
    }
}

// ---------------- fused attention (coalesced probs via fp32 LDS staging) ----------------
__global__ __launch_bounds__(256) void attn_k(const u16* __restrict__ qkv,
        const u16* __restrict__ kpb, const u16* __restrict__ vpb,
        const int* __restrict__ currp, float* __restrict__ probs, u16* __restrict__ ctxb) {
    int sb = blockIdx.x, h = blockIdx.y, b = blockIdx.z;
    int cr = *currp;
    __shared__ u16 vpl[64 * 80];
    __shared__ u16 pl[64 * 80];
    __shared__ __align__(16) u16 kbuf[8192];   // kpl (pitch 80) -> reused as plf f32[64][64]
    int t = threadIdx.x, lane = t & 63, w = t >> 6;

    {
        int r = t >> 2, d0 = (t & 3) * 16;
        size_t ob = (size_t)(b * 16 + h) * 4096 + t * 16;
        u16x8 k0 = *(const u16x8*)(kpb + ob), k1 = *(const u16x8*)(kpb + ob + 8);
        u16x8 v0 = *(const u16x8*)(vpb + ob), v1 = *(const u16x8*)(vpb + ob + 8);
        *(u16x8*)&kbuf[r * 80 + d0]     = k0;
        *(u16x8*)&kbuf[r * 80 + d0 + 8] = k1;
        *(u16x8*)&vpl[r * 80 + d0]     = v0;
        *(u16x8*)&vpl[r * 80 + d0 + 8] = v1;
    }
    __syncthreads();

    const u16* qp = qkv + (size_t)(b * 2048 + sb * 64 + w * 16 + (lane & 15)) * 3072 + h * 64 + ((lane >> 4) << 3);
    s16x8 q0 = *(const s16x8*)qp;
    s16x8 q1 = *(const s16x8*)(qp + 32);
    f32x4 zero4 = {0.f, 0.f, 0.f, 0.f};
    f32x4 sc[4];
    #pragma unroll
    for (int j = 0; j < 4; ++j) {
        sc[j] = zero4;
        s16x8 k0 = *(const s16x8*)&kbuf[(j * 16 + (lane & 15)) * 80 + ((lane >> 4) << 3)];
        s16x8 k1 = *(const s16x8*)&kbuf[(j * 16 + (lane & 15)) * 80 + 32 + ((lane >> 4) << 3)];
        sc[j] = mfma16(q0, k0, sc[j]);
        sc[j] = mfma16(q1, k1, sc[j]);
    }

    const float scale = 0.125f;
    float p_[4][4];
    #pragma unroll
    for (int v = 0; v < 4; ++v) {
        float m = -3.0e38f;
        #pragma unroll
        for (int j = 0; j < 4; ++j) {
            int rr = j * 16 + (lane & 15);
            if (rr < cr) m = fmaxf(m, sc[j][v] * scale);
        }
        m = fmaxf(m, __shfl_xor(m, 1));
        m = fmaxf(m, __shfl_xor(m, 2));
        m = fmaxf(m, __shfl_xor(m, 4));
        m = fmaxf(m, __shfl_xor(m, 8));
        float s = 0.f;
        #pragma unroll
        for (int j = 0; j < 4; ++j) {
            int rr = j * 16 + (lane & 15);
            float p = (rr < cr) ? __expf(sc[j][v] * scale - m) : 0.f;
            p_[j][v] = p; s += p;
        }
        s += __shfl_xor(s, 1); s += __shfl_xor(s, 2);
        s += __shfl_xor(s, 4); s += __shfl_xor(s, 8);
        float inv = 1.f / s;
        #pragma unroll
        for (int j = 0; j < 4; ++j) p_[j][v] *= inv;
    }

    __syncthreads();   // all waves done reading kbuf (scores) before overlay write

    float* pf = (float*)kbuf;
    int srow = w * 16 + ((lane >> 4) << 2);
    #pragma unroll
    for (int v = 0; v < 4; ++v) {
        #pragma unroll
        for (int j = 0; j < 4; ++j) {
            int rr = j * 16 + (lane & 15);
            pf[(srow + v) * 64 + rr] = p_[j][v];
            pl[(srow + v) * 80 + rr] = f2bf(p_[j][v]);
        }
    }
    __syncthreads();

    f32x4 co[4] = {zero4, zero4, zero4, zero4};
    #pragma unroll
    for (int ks = 0; ks < 2; ++ks) {
        s16x8 pa = *(const s16x8*)&pl[(w * 16 + (lane & 15)) * 80 + ks * 32 + ((lane >> 4) << 3)];
        #pragma unroll
        for (int n = 0; n < 4; ++n) {
            s16x8 vf = *(const s16x8*)&vpl[(n * 16 + (lane & 15)) * 80 + ks * 32 + ((lane >> 4) << 3)];
            co[n] = mfma16(pa, vf, co[n]);
        }
    }
    #pragma unroll
    for (int n = 0; n < 4; ++n)
        #pragma unroll
        for (int v = 0; v < 4; ++v)
            ctxb[(size_t)((b * 2048 + sb * 64 + srow + v) * 16 + h) * 64 + n * 16 + (lane & 15)] = f2bf(co[n][v]);

    {   // coalesced probs write: thread t -> row t>>2, 64B contiguous
        int prow = t >> 2, pcol0 = (t & 3) * 16;
        size_t pbase = (size_t)((b * 16 + h) * 2048 + sb * 64 + prow) * 64 + pcol0;
        #pragma unroll
        for (int u = 0; u < 4; ++u) {
            float4 pv4 = *(const float4*)&pf[prow * 64 + pcol0 + u * 4];
            *(float4*)&probs[pbase + u * 4] = pv4;
        }
    }
}

// ---------------- launch ----------------
extern "C" void kernel_launch(void* const* d_in, const int* in_sizes, int n_in,
                              void* d_out, int out_size, void* d_ws, size_t ws_size,
                              hipStream_t stream) {
    const float* hs = (const float*)d_in[0];
    const float* Wq = (const float*)d_in[1];
    const float* bq = (const float*)d_in[2];
    const float* Wk = (const float*)d_in[3];
    const float* bk = (const float*)d_in[4];
    const float* Wv = (const float*)d_in[5];
    const float* bv = (const float*)d_in[6];
    const float* Wo = (const float*)d_in[7];
    const float* bo = (const float*)d_in[8];
    const float* pk = (const float*)d_in[9];
    const float* pv = (const float*)d_in[10];
    float* out = (float*)d_out;
    char* w = (char*)d_ws;

    u16* hsb   = (u16*)(w + 0);                 // 16 MB; later vp_part then ctxb
    float* vp_part = (float*)(w + 0);
    u16* ctxb  = (u16*)(w + 0);
    u16* wqb   = (u16*)(w + 16777216);          // 8 MB: Wq,Wk,Wv (=Wcat), Wo
    u16* ptb   = (u16*)(w + 25165824);          // 4 MB
    u16* pvtb  = (u16*)(w + 29360128);          // 4 MB
    u16* qkvb  = (u16*)(w + 33554432);          // 48 MB: [8192][3072] bf16 (q|k|v)
    float* kp_part = (float*)(w + 83886080);    // 4 MB
    float* biascat = (float*)(w + 92274688);    // 12 KB
    double* red    = (double*)(w + 92291072);   // 16 KB
    int* currp     = (int*)(w + 92307456);
    u16* kpb   = (u16*)(w + 92307520);          // 0.5 MB
    u16* vpb   = (u16*)(w + 92831808);          // 0.5 MB

    prep_k<<<4097, 256, 0, stream>>>(hs, hsb, red, Wq, Wk, Wv, Wo, wqb,
                                     pk, pv, ptb, pvtb, bq, bk, bv, biascat);

    qkv_gemm_k<<<256, 512, 0, stream>>>(hsb, wqb, biascat, qkvb);

    proj_einsum_k<<<dim3(4, 16, 8), 256, 0, stream>>>(qkvb, ptb, pvtb, kp_part, vp_part);
    reduce_kv_k<<<dim3(16, 4, 4), 256, 0, stream>>>(kp_part, vp_part, kpb, vpb,
                                                    red, currp, out + 16777216);

    attn_k<<<dim3(32, 16, 4), 256, 0, stream>>>(qkvb, kpb, vpb, currp,
                                                out + 8388608, ctxb);

    out_gemm_k<<<256, 512, 0, stream>>>(ctxb, wqb + 3145728, bo, out);
}

// Round 12
// 136.984 us; speedup vs baseline: 1.0420x; 1.0420x over previous
//
#include <hip/hip_runtime.h>

// DynamicLinBertSelfAttention on MI355X (gfx950).  R12 = R10 verbatim (measured
// best, 137.1us). R11's attn-probs-staging + out_gemm-triple-buffer both
// regressed (+5.6us) and are reverted.
//
// d_out layout (fp32): [0,8388608) output, [8388608,16777216) attn_probs, [16777216] curr_r.

typedef unsigned short u16;
typedef short s16x8 __attribute__((ext_vector_type(8)));
typedef unsigned short u16x8 __attribute__((ext_vector_type(8)));
typedef unsigned short u16x4 __attribute__((ext_vector_type(4)));
typedef float f32x4 __attribute__((ext_vector_type(4)));

#define GLL16(gp, lp) __builtin_amdgcn_global_load_lds( \
    (const __attribute__((address_space(1))) void*)(gp), \
    (__attribute__((address_space(3))) void*)(lp), 16, 0, 0)

__device__ __forceinline__ u16 f2bf(float f) {
    unsigned u = __float_as_uint(f);
    u += 0x7fffu + ((u >> 16) & 1u);   // RNE (inputs finite)
    return (u16)(u >> 16);
}

__device__ __forceinline__ f32x4 mfma16(s16x8 a, s16x8 b, f32x4 c) {
    return __builtin_amdgcn_mfma_f32_16x16x32_bf16(a, b, c, 0, 0, 0);
}

// ---------------- K1: fused prep — hs cast+var, weight cast, proj transpose, biases ----------------
__global__ __launch_bounds__(256) void prep_k(const float* __restrict__ hs,
        u16* __restrict__ hsb, double* __restrict__ red,
        const float* __restrict__ w0, const float* __restrict__ w1,
        const float* __restrict__ w2, const float* __restrict__ w3,
        u16* __restrict__ wout,
        const float* __restrict__ p0, const float* __restrict__ p1,
        u16* __restrict__ q0, u16* __restrict__ q1,
        const float* __restrict__ bq, const float* __restrict__ bk,
        const float* __restrict__ bv, float* __restrict__ biascat) {
    __shared__ float tl[64][65];
    __shared__ double sa[256], sb[256];
    int bid = blockIdx.x, t = threadIdx.x;
    if (bid < 1024) {                 // hs cast + fp64 variance partials
        size_t base = (size_t)bid * 8192;
        double s = 0.0, s2 = 0.0;
        #pragma unroll
        for (int i = 0; i < 4; ++i) {
            size_t idx = base + (size_t)i * 2048 + (size_t)t * 8;
            float4 a = *(const float4*)(hs + idx);
            float4 c = *(const float4*)(hs + idx + 4);
            s  += (double)a.x + (double)a.y + (double)a.z + (double)a.w
                + (double)c.x + (double)c.y + (double)c.z + (double)c.w;
            s2 += (double)a.x * a.x + (double)a.y * a.y + (double)a.z * a.z + (double)a.w * a.w
                + (double)c.x * c.x + (double)c.y * c.y + (double)c.z * c.z + (double)c.w * c.w;
            u16x8 o;
            o[0] = f2bf(a.x); o[1] = f2bf(a.y); o[2] = f2bf(a.z); o[3] = f2bf(a.w);
            o[4] = f2bf(c.x); o[5] = f2bf(c.y); o[6] = f2bf(c.z); o[7] = f2bf(c.w);
            *(u16x8*)(hsb + idx) = o;
        }
        sa[t] = s; sb[t] = s2;
        __syncthreads();
        for (int o = 128; o > 0; o >>= 1) {
            if (t < o) { sa[t] += sa[t + o]; sb[t] += sb[t + o]; }
            __syncthreads();
        }
        if (t == 0) { red[bid * 2] = sa[0]; red[bid * 2 + 1] = sb[0]; }
    } else if (bid < 3072) {          // weight cast
        int bid2 = bid - 1024;
        int mat = bid2 >> 9;
        int off = ((bid2 & 511) * 256 + t) * 8;
        const float* src = (mat == 0) ? w0 : (mat == 1) ? w1 : (mat == 2) ? w2 : w3;
        float4 a = *(const float4*)(src + off);
        float4 c = *(const float4*)(src + off + 4);
        u16x8 o;
        o[0] = f2bf(a.x); o[1] = f2bf(a.y); o[2] = f2bf(a.z); o[3] = f2bf(a.w);
        o[4] = f2bf(c.x); o[5] = f2bf(c.y); o[6] = f2bf(c.z); o[7] = f2bf(c.w);
        *(u16x8*)(wout + (size_t)mat * 1048576 + off) = o;
    } else if (bid < 4096) {          // proj transpose-cast
        int bid2 = bid - 3072;
        int which = bid2 >> 9, bi = bid2 & 511;
        const float* p = which ? p1 : p0;
        u16* pt = which ? q1 : q0;
        int h = bi >> 5, lb = bi & 31;
        {
            int l = t >> 2, r0 = (t & 3) * 16;
            const float* src = p + ((size_t)(h * 2048 + lb * 64 + l)) * 64 + r0;
            #pragma unroll
            for (int u = 0; u < 4; ++u) {
                float4 v = *(const float4*)(src + u * 4);
                tl[l][r0 + u * 4 + 0] = v.x; tl[l][r0 + u * 4 + 1] = v.y;
                tl[l][r0 + u * 4 + 2] = v.z; tl[l][r0 + u * 4 + 3] = v.w;
            }
        }
        __syncthreads();
        {
            int r = t >> 2, l0 = (t & 3) * 16;
            u16x8 o0, o1;
            #pragma unroll
            for (int j = 0; j < 8; ++j) { o0[j] = f2bf(tl[l0 + j][r]); o1[j] = f2bf(tl[l0 + 8 + j][r]); }
            u16* dst = pt + ((size_t)(h * 64 + r)) * 2048 + lb * 64 + l0;
            *(u16x8*)dst = o0;
            *(u16x8*)(dst + 8) = o1;
        }
    } else {                          // bias concat [3072]
        for (int i = t; i < 3072; i += 256) {
            float v = (i < 1024) ? bq[i] : (i < 2048) ? bk[i - 1024] : bv[i - 2048];
            biascat[i] = v;
        }
    }
}

// ---------------- QKV GEMM (R7 triple-buffer, measured 56us) ----------------
__global__ __launch_bounds__(512, 2) void qkv_gemm_k(const u16* __restrict__ Ag,
        const u16* __restrict__ Wcat, const float* __restrict__ biascat,
        u16* __restrict__ C) {
    __shared__ u16 lds[61440];
    int bid = blockIdx.x;
    int swz = (bid & 7) * 32 + (bid >> 3);    // XCD-aware (256 % 8 == 0)
    int bm = swz >> 3, bn = swz & 7;
    int t = threadIdx.x, lane = t & 63, w = t >> 6, wr = w >> 2, wc = w & 3;

    int srow = w * 16 + (lane >> 2);
    int slog = (((lane & 3) ^ ((lane >> 3) & 3)) << 3);
    const u16* asrc0 = Ag + (size_t)(bm * 256 + srow) * 1024 + slog;
    const u16* bsrc0 = Wcat + (size_t)(bn * 384 + srow) * 1024 + slog;

#define STAGEA(kts, h) GLL16(asrc0 + (h) * 131072 + (kts) * 32, \
                             &lds[((kts) % 3) * 20480 + (h) * 4096 + w * 512])
#define STAGEB(kts, h) GLL16(bsrc0 + (h) * 131072 + (kts) * 32, \
                             &lds[((kts) % 3) * 20480 + 8192 + (h) * 4096 + w * 512])

    int pcol = (((lane >> 4) ^ (((lane & 15) >> 1) & 3)) << 3);
    int arow0 = (wr * 128 + (lane & 15)) * 32 + pcol;
    int brow0 = 8192 + (wc * 96 + (lane & 15)) * 32 + pcol;

    f32x4 zero4 = {0.f, 0.f, 0.f, 0.f};
    f32x4 acc[8][6];
    #pragma unroll
    for (int m = 0; m < 8; ++m)
        #pragma unroll
        for (int n = 0; n < 6; ++n) acc[m][n] = zero4;

    STAGEA(0, 0); STAGEA(0, 1); STAGEB(0, 0); STAGEB(0, 1); STAGEB(0, 2);
    STAGEA(1, 0); STAGEA(1, 1); STAGEB(1, 0); STAGEB(1, 1); STAGEB(1, 2);
    asm volatile("s_waitcnt vmcnt(5)" ::: "memory");
    __builtin_amdgcn_s_barrier();
    asm volatile("" ::: "memory");

    for (int kt = 0; kt < 32; ++kt) {
        int b3 = (kt % 3) * 20480;
        int abase = b3 + arow0;
        int bbase = b3 + brow0;
        s16x8 af[8], bf0, bf1, bf2;

        // ---- phase 0: all A frags + B n0,n1,n2 ; stage kt+2 A0,A1,B0 ----
        #pragma unroll
        for (int m = 0; m < 8; ++m) af[m] = *(const s16x8*)&lds[abase + m * 512];
        bf0 = *(const s16x8*)&lds[bbase];
        bf1 = *(const s16x8*)&lds[bbase + 512];
        bf2 = *(const s16x8*)&lds[bbase + 1024];
        if (kt < 30) { STAGEA(kt + 2, 0); STAGEA(kt + 2, 1); STAGEB(kt + 2, 0); }
        __builtin_amdgcn_s_barrier();
        asm volatile("s_waitcnt lgkmcnt(0)" ::: "memory");
        __builtin_amdgcn_s_setprio(1);
        #pragma unroll
        for (int m = 0; m < 8; ++m) {
            acc[m][0] = mfma16(af[m], bf0, acc[m][0]);
            acc[m][1] = mfma16(af[m], bf1, acc[m][1]);
            acc[m][2] = mfma16(af[m], bf2, acc[m][2]);
        }
        __builtin_amdgcn_s_setprio(0);
        __builtin_amdgcn_s_barrier();
        asm volatile("" ::: "memory");

        // ---- phase 1: B n3,n4,n5 ; stage kt+2 B1,B2 ; counted vmcnt after MFMA ----
        bf0 = *(const s16x8*)&lds[bbase + 1536];
        bf1 = *(const s16x8*)&lds[bbase + 2048];
        bf2 = *(const s16x8*)&lds[bbase + 2560];
        if (kt < 30) { STAGEB(kt + 2, 1); STAGEB(kt + 2, 2); }
        __builtin_amdgcn_s_barrier();
        asm volatile("s_waitcnt lgkmcnt(0)" ::: "memory");
        __builtin_amdgcn_s_setprio(1);
        #pragma unroll
        for (int m = 0; m < 8; ++m) {
            acc[m][3] = mfma16(af[m], bf0, acc[m][3]);
            acc[m][4] = mfma16(af[m], bf1, acc[m][4]);
            acc[m][5] = mfma16(af[m], bf2, acc[m][5]);
        }
        __builtin_amdgcn_s_setprio(0);
        if (kt < 30) { asm volatile("s_waitcnt vmcnt(5)" ::: "memory"); }
        else if (kt == 30) { asm volatile("s_waitcnt vmcnt(0)" ::: "memory"); }
        __builtin_amdgcn_s_barrier();
        asm volatile("" ::: "memory");
    }

    float bias[6];
    #pragma unroll
    for (int n = 0; n < 6; ++n)
        bias[n] = biascat[bn * 384 + wc * 96 + n * 16 + (lane & 15)];
    #pragma unroll
    for (int m = 0; m < 8; ++m) {
        int row0 = bm * 256 + wr * 128 + m * 16 + ((lane >> 4) << 2);
        #pragma unroll
        for (int n = 0; n < 6; ++n) {
            int col = bn * 384 + wc * 96 + n * 16 + (lane & 15);
            #pragma unroll
            for (int v = 0; v < 4; ++v)
                C[(size_t)(row0 + v) * 3072 + col] = f2bf(acc[m][n][v] + bias[n]);
        }
    }
#undef STAGEA
#undef STAGEB
}

// ---------------- out-proj GEMM: C[8192][1024] f32 = ctx @ Wo^T + bo ----------------
__global__ __launch_bounds__(512, 2) void out_gemm_k(const u16* __restrict__ Ag,
        const u16* __restrict__ Bg, const float* __restrict__ biasg,
        float* __restrict__ Cg) {
    __shared__ u16 lds[24576];   // A [2][256][32] @0, B [2][128][32] @16384
    int bid = blockIdx.x;
    int swz = (bid & 7) * 32 + (bid >> 3);
    int bm = swz >> 3, bn = swz & 7;
    int t = threadIdx.x, lane = t & 63, w = t >> 6, wr = w >> 1, wc = w & 1;

    int srow = w * 16 + (lane >> 2);
    int slog = (((lane & 3) ^ ((lane >> 3) & 3)) << 3);
    const u16* asrc0 = Ag + (size_t)(bm * 256 + srow) * 1024 + slog;
    const u16* bsrc0 = Bg + (size_t)(bn * 128 + srow) * 1024 + slog;

#define STAGEA(kts, h) GLL16(asrc0 + (h) * 131072 + (kts) * 32, \
                             &lds[(((kts) & 1) * 8192) + (h) * 4096 + w * 512])
#define STAGEB(kts) GLL16(bsrc0 + (kts) * 32, \
                          &lds[16384 + (((kts) & 1) * 4096) + w * 512])

    int pcol = (((lane >> 4) ^ (((lane & 15) >> 1) & 3)) << 3);
    int arow0 = (wr * 64 + (lane & 15)) * 32 + pcol;
    int brow0 = 16384 + (wc * 64 + (lane & 15)) * 32 + pcol;

    f32x4 zero4 = {0.f, 0.f, 0.f, 0.f};
    f32x4 acc[4][4];
    #pragma unroll
    for (int m = 0; m < 4; ++m)
        #pragma unroll
        for (int n = 0; n < 4; ++n) acc[m][n] = zero4;

    STAGEA(0, 0); STAGEA(0, 1); STAGEB(0);
    STAGEA(1, 0); STAGEA(1, 1);
    asm volatile("s_waitcnt vmcnt(2)" ::: "memory");
    __builtin_amdgcn_s_barrier();
    asm volatile("" ::: "memory");

    for (int kt = 0; kt < 32; ++kt) {
        int abase = (kt & 1) * 8192 + arow0;
        int bbase = (kt & 1) * 4096 + brow0;
        s16x8 af[4], bf0, bf1;

        #pragma unroll
        for (int m = 0; m < 4; ++m) af[m] = *(const s16x8*)&lds[abase + m * 512];
        bf0 = *(const s16x8*)&lds[bbase];
        bf1 = *(const s16x8*)&lds[bbase + 512];
        if (kt < 31) STAGEB(kt + 1);
        asm volatile("s_waitcnt lgkmcnt(0)" ::: "memory");
        __builtin_amdgcn_s_barrier();
        __builtin_amdgcn_s_setprio(1);
        #pragma unroll
        for (int m = 0; m < 4; ++m) {
            acc[m][0] = mfma16(af[m], bf0, acc[m][0]);
            acc[m][1] = mfma16(af[m], bf1, acc[m][1]);
        }
        __builtin_amdgcn_s_setprio(0);
        __builtin_amdgcn_s_barrier();
        asm volatile("" ::: "memory");

        bf0 = *(const s16x8*)&lds[bbase + 1024];
        bf1 = *(const s16x8*)&lds[bbase + 1536];
        if (kt < 30) { STAGEA(kt + 2, 0); STAGEA(kt + 2, 1); }
        if (kt < 30) { asm volatile("s_waitcnt vmcnt(2)" ::: "memory"); }
        else if (kt == 30) { asm volatile("s_waitcnt vmcnt(0)" ::: "memory"); }
        asm volatile("s_waitcnt lgkmcnt(0)" ::: "memory");
        __builtin_amdgcn_s_barrier();
        __builtin_amdgcn_s_setprio(1);
        #pragma unroll
        for (int m = 0; m < 4; ++m) {
            acc[m][2] = mfma16(af[m], bf0, acc[m][2]);
            acc[m][3] = mfma16(af[m], bf1, acc[m][3]);
        }
        __builtin_amdgcn_s_setprio(0);
        __builtin_amdgcn_s_barrier();
        asm volatile("" ::: "memory");
    }

    float bias[4];
    #pragma unroll
    for (int n = 0; n < 4; ++n)
        bias[n] = biasg[bn * 128 + wc * 64 + n * 16 + (lane & 15)];
    #pragma unroll
    for (int m = 0; m < 4; ++m) {
        int row0 = bm * 256 + wr * 64 + m * 16 + ((lane >> 4) << 2);
        #pragma unroll
        for (int n = 0; n < 4; ++n) {
            int col = bn * 128 + wc * 64 + n * 16 + (lane & 15);
            #pragma unroll
            for (int v = 0; v < 4; ++v)
                Cg[(size_t)(row0 + v) * 1024 + col] = acc[m][n][v] + bias[n];
        }
    }
#undef STAGEA
#undef STAGEB
}

// ---------------- proj einsum v4: c=4 chunks of 512 l ----------------
__global__ __launch_bounds__(256) void proj_einsum_k(const u16* __restrict__ qkv,
        const u16* __restrict__ pt0, const u16* __restrict__ pt1,
        float* __restrict__ out0, float* __restrict__ out1) {
    __shared__ u16 kt[512 * 66];
    int c = blockIdx.x, h = blockIdx.y, z = blockIdx.z;
    int which = z >> 2, b = z & 3;
    const u16* kv = qkv + 1024 + which * 1024;
    const u16* pt = which ? pt1 : pt0;
    float* outp = which ? out1 : out0;
    int t = threadIdx.x, lane = t & 63, w = t >> 6;

    int tl = t >> 3, sd = (t & 7) * 8;
    const u16* kvp = kv + (size_t)(b * 2048 + c * 512 + tl) * 3072 + h * 64 + sd;
    #pragma unroll
    for (int half = 0; half < 2; ++half) {
        s16x8 g[8];
        #pragma unroll
        for (int i = 0; i < 8; ++i)
            g[i] = *(const s16x8*)(kvp + (size_t)(half * 8 + i) * 98304);
        #pragma unroll
        for (int i = 0; i < 8; ++i)
            *(s16x8*)&kt[(tl + 32 * (half * 8 + i)) * 66 + sd] = g[i];
    }
    __syncthreads();

    f32x4 zero4 = {0.f, 0.f, 0.f, 0.f};
    f32x4 acc[4] = {zero4, zero4, zero4, zero4};
    const u16* ptb_ = pt + (size_t)(h * 64 + (lane & 15)) * 2048 + c * 512 + ((lane >> 4) << 3);
    int gcol = w * 16 + (lane & 15);
    int gk0 = (lane >> 4) << 3;

    #pragma unroll
    for (int ks = 0; ks < 16; ++ks) {
        s16x8 bf;
        int kb = (ks * 32 + gk0) * 66 + gcol;
        #pragma unroll
        for (int j = 0; j < 8; ++j) bf[j] = (short)kt[kb + j * 66];
        #pragma unroll
        for (int m = 0; m < 4; ++m) {
            s16x8 af = *(const s16x8*)(ptb_ + (size_t)m * 32768 + ks * 32);
            acc[m] = mfma16(af, bf, acc[m]);
        }
    }

    float* ob = outp + (size_t)((c * 4 + b) * 16 + h) * 4096;
    #pragma unroll
    for (int m = 0; m < 4; ++m)
        #pragma unroll
        for (int v = 0; v < 4; ++v)
            ob[(m * 16 + ((lane >> 4) << 2) + v) * 64 + w * 16 + (lane & 15)] = acc[m][v];
}

// ---------------- reduce chunk partials -> bf16 KP [r][d] and VP [d][r]; +curr_r ----------------
__global__ __launch_bounds__(256) void reduce_kv_k(const float* __restrict__ kp_part,
        const float* __restrict__ vp_part, u16* __restrict__ kpb, u16* __restrict__ vpb,
        const double* __restrict__ red, int* __restrict__ currp, float* __restrict__ outr) {
    int h = blockIdx.x, b = blockIdx.y, zr = blockIdx.z, t = threadIdx.x;
    int r = zr * 16 + (t >> 4), d0 = (t & 15) * 4;
    int base = (b * 16 + h) * 4096 + r * 64 + d0;
    float4 sk = {0.f, 0.f, 0.f, 0.f}, sv = {0.f, 0.f, 0.f, 0.f};
    #pragma unroll
    for (int c = 0; c < 4; ++c) {
        float4 a = *(const float4*)&kp_part[c * 262144 + base];
        float4 g = *(const float4*)&vp_part[c * 262144 + base];
        sk.x += a.x; sk.y += a.y; sk.z += a.z; sk.w += a.w;
        sv.x += g.x; sv.y += g.y; sv.z += g.z; sv.w += g.w;
    }
    size_t ob = (size_t)(b * 16 + h) * 4096;
    u16x4 ok;
    ok[0] = f2bf(sk.x); ok[1] = f2bf(sk.y); ok[2] = f2bf(sk.z); ok[3] = f2bf(sk.w);
    *(u16x4*)&kpb[ob + r * 64 + d0] = ok;
    vpb[ob + (size_t)(d0 + 0) * 64 + r] = f2bf(sv.x);
    vpb[ob + (size_t)(d0 + 1) * 64 + r] = f2bf(sv.y);
    vpb[ob + (size_t)(d0 + 2) * 64 + r] = f2bf(sv.z);
    vpb[ob + (size_t)(d0 + 3) * 64 + r] = f2bf(sv.w);

    if (h == 0 && b == 0 && zr == 0) {   // curr_r (deterministic fp64)
        int lane = t & 63, bb = t >> 6;
        double s = 0.0, s2 = 0.0;
        #pragma unroll
        for (int j = 0; j < 4; ++j) {
            int idx = bb * 256 + j * 64 + lane;
            s += red[idx * 2]; s2 += red[idx * 2 + 1];
        }
        #pragma unroll
        for (int o = 1; o < 64; o <<= 1) { s += __shfl_xor(s, o); s2 += __shfl_xor(s2, o); }
        __shared__ double vs[4];
        if (lane == 0) {
            const double N = 2097152.0;
            vs[bb] = (s2 - s * s / N) / (N - 1.0);
        }
        __syncthreads();
        if (t == 0) {
            double mn = vs[0], mx = vs[0];
            for (int i = 1; i < 4; ++i) { mn = fmin(mn, vs[i]); mx = fmax(mx, vs[i]); }
            double mean = 0.0;
            for (int i = 0; i < 4; ++i) mean += (vs[i] - mn) / (mx - mn + 1e-6);
            mean *= 0.25;
            double rr = rint(16.0 + mean * 48.0);
            *currp = (int)rr;
            *outr = (float)rr;
        }
    }
}

// ---------------- fused attention ----------------
__global__ __launch_bounds__(256) void attn_k(const u16* __restrict__ qkv,
        const u16* __restrict__ kpb, const u16* __restrict__ vpb,
        const int* __restrict__ currp, float* __restrict__ probs, u16* __restrict__ ctxb) {
    int sb = blockIdx.x, h = blockIdx.y, b = blockIdx.z;
    int cr = *currp;
    __shared__ u16 kpl[64 * 80];
    __shared__ u16 vpl[64 * 80];
    __shared__ u16 pl[64 * 80];
    int t = threadIdx.x, lane = t & 63, w = t >> 6;

    {
        int r = t >> 2, d0 = (t & 3) * 16;
        size_t ob = (size_t)(b * 16 + h) * 4096 + t * 16;
        u16x8 k0 = *(const u16x8*)(kpb + ob), k1 = *(const u16x8*)(kpb + ob + 8);
        u16x8 v0 = *(const u16x8*)(vpb + ob), v1 = *(const u16x8*)(vpb + ob + 8);
        *(u16x8*)&kpl[r * 80 + d0]     = k0;
        *(u16x8*)&kpl[r * 80 + d0 + 8] = k1;
        *(u16x8*)&vpl[r * 80 + d0]     = v0;
        *(u16x8*)&vpl[r * 80 + d0 + 8] = v1;
    }
    __syncthreads();

    const u16* qp = qkv + (size_t)(b * 2048 + sb * 64 + w * 16 + (lane & 15)) * 3072 + h * 64 + ((lane >> 4) << 3);
    s16x8 q0 = *(const s16x8*)qp;
    s16x8 q1 = *(const s16x8*)(qp + 32);
    f32x4 zero4 = {0.f, 0.f, 0.f, 0.f};
    f32x4 sc[4];
    #pragma unroll
    for (int j = 0; j < 4; ++j) {
        sc[j] = zero4;
        s16x8 k0 = *(const s16x8*)&kpl[(j * 16 + (lane & 15)) * 80 + ((lane >> 4) << 3)];
        s16x8 k1 = *(const s16x8*)&kpl[(j * 16 + (lane & 15)) * 80 + 32 + ((lane >> 4) << 3)];
        sc[j] = mfma16(q0, k0, sc[j]);
        sc[j] = mfma16(q1, k1, sc[j]);
    }

    const float scale = 0.125f;
    float p_[4][4];
    #pragma unroll
    for (int v = 0; v < 4; ++v) {
        float m = -3.0e38f;
        #pragma unroll
        for (int j = 0; j < 4; ++j) {
            int rr = j * 16 + (lane & 15);
            if (rr < cr) m = fmaxf(m, sc[j][v] * scale);
        }
        m = fmaxf(m, __shfl_xor(m, 1));
        m = fmaxf(m, __shfl_xor(m, 2));
        m = fmaxf(m, __shfl_xor(m, 4));
        m = fmaxf(m, __shfl_xor(m, 8));
        float s = 0.f;
        #pragma unroll
        for (int j = 0; j < 4; ++j) {
            int rr = j * 16 + (lane & 15);
            float p = (rr < cr) ? __expf(sc[j][v] * scale - m) : 0.f;
            p_[j][v] = p; s += p;
        }
        s += __shfl_xor(s, 1); s += __shfl_xor(s, 2);
        s += __shfl_xor(s, 4); s += __shfl_xor(s, 8);
        float inv = 1.f / s;
        #pragma unroll
        for (int j = 0; j < 4; ++j) p_[j][v] *= inv;
    }

    int srow = w * 16 + ((lane >> 4) << 2);
    #pragma unroll
    for (int v = 0; v < 4; ++v) {
        int sg = sb * 64 + srow + v;
        #pragma unroll
        for (int j = 0; j < 4; ++j) {
            int rr = j * 16 + (lane & 15);
            probs[(size_t)((b * 16 + h) * 2048 + sg) * 64 + rr] = p_[j][v];
            pl[(srow + v) * 80 + rr] = f2bf(p_[j][v]);
        }
    }
    __syncthreads();

    f32x4 co[4] = {zero4, zero4, zero4, zero4};
    #pragma unroll
    for (int ks = 0; ks < 2; ++ks) {
        s16x8 pa = *(const s16x8*)&pl[(w * 16 + (lane & 15)) * 80 + ks * 32 + ((lane >> 4) << 3)];
        #pragma unroll
        for (int n = 0; n < 4; ++n) {
            s16x8 vf = *(const s16x8*)&vpl[(n * 16 + (lane & 15)) * 80 + ks * 32 + ((lane >> 4) << 3)];
            co[n] = mfma16(pa, vf, co[n]);
        }
    }
    #pragma unroll
    for (int n = 0; n < 4; ++n)
        #pragma unroll
        for (int v = 0; v < 4; ++v)
            ctxb[(size_t)((b * 2048 + sb * 64 + srow + v) * 16 + h) * 64 + n * 16 + (lane & 15)] = f2bf(co[n][v]);
}

// ---------------- launch ----------------
extern "C" void kernel_launch(void* const* d_in, const int* in_sizes, int n_in,
                              void* d_out, int out_size, void* d_ws, size_t ws_size,
                              hipStream_t stream) {
    const float* hs = (const float*)d_in[0];
    const float* Wq = (const float*)d_in[1];
    const float* bq = (const float*)d_in[2];
    const float* Wk = (const float*)d_in[3];
    const float* bk = (const float*)d_in[4];
    const float* Wv = (const float*)d_in[5];
    const float* bv = (const float*)d_in[6];
    const float* Wo = (const float*)d_in[7];
    const float* bo = (const float*)d_in[8];
    const float* pk = (const float*)d_in[9];
    const float* pv = (const float*)d_in[10];
    float* out = (float*)d_out;
    char* w = (char*)d_ws;

    u16* hsb   = (u16*)(w + 0);                 // 16 MB; later vp_part then ctxb
    float* vp_part = (float*)(w + 0);
    u16* ctxb  = (u16*)(w + 0);
    u16* wqb   = (u16*)(w + 16777216);          // 8 MB: Wq,Wk,Wv (=Wcat), Wo
    u16* ptb   = (u16*)(w + 25165824);          // 4 MB
    u16* pvtb  = (u16*)(w + 29360128);          // 4 MB
    u16* qkvb  = (u16*)(w + 33554432);          // 48 MB: [8192][3072] bf16 (q|k|v)
    float* kp_part = (float*)(w + 83886080);    // 4 MB
    float* biascat = (float*)(w + 92274688);    // 12 KB
    double* red    = (double*)(w + 92291072);   // 16 KB
    int* currp     = (int*)(w + 92307456);
    u16* kpb   = (u16*)(w + 92307520);          // 0.5 MB
    u16* vpb   = (u16*)(w + 92831808);          // 0.5 MB

    prep_k<<<4097, 256, 0, stream>>>(hs, hsb, red, Wq, Wk, Wv, Wo, wqb,
                                     pk, pv, ptb, pvtb, bq, bk, bv, biascat);

    qkv_gemm_k<<<256, 512, 0, stream>>>(hsb, wqb, biascat, qkvb);

    proj_einsum_k<<<dim3(4, 16, 8), 256, 0, stream>>>(qkvb, ptb, pvtb, kp_part, vp_part);
    reduce_kv_k<<<dim3(16, 4, 4), 256, 0, stream>>>(kp_part, vp_part, kpb, vpb,
                                                    red, currp, out + 16777216);

    attn_k<<<dim3(32, 16, 4), 256, 0, stream>>>(qkvb, kpb, vpb, currp,
                                                out + 8388608, ctxb);

    out_gemm_k<<<256, 512, 0, stream>>>(ctxb, wqb + 3145728, bo, out);
}